// Round 11
// baseline (997.108 us; speedup 1.0000x reference)
//
#include <hip/hip_runtime.h>
#include <hip/hip_bf16.h>
#include <math.h>

// Problem constants
#define NROWS 8192
#define DDAT  784
#define LDK_D 800            // padded K (multiple of 32)
#define DLAT  64
#define TILE  128            // output tile per block
#define NBT   64             // zz grid dim: 8192/128
#define NPARTS (NBT * NBT)   // 4096 zz partial slots
#define NBTC  128            // concat rows 16384 / 128
// Supertile decomposition of the 128x128 block triangle:
#define SG    8              // supertile = 8x8 blocks
#define NSB   (NBTC / SG)    // 16 supertiles per dim
#define NST   (NSB * (NSB + 1) / 2)   // 136 supertiles (incl diagonal)
#define NSLOT (NST * SG * SG)         // 8704 launch slots
#define CHUNK (NSLOT / 8)             // 1088 per XCD (exact)

typedef __attribute__((ext_vector_type(8))) short bf16x8;
typedef __attribute__((ext_vector_type(4))) float f32x4;

// Pin a scalar kernel arg into a VGPR: prevents the backend from fusing
// alpha + beta*d into a v_fma reading TWO SGPRs (constant-bus violation,
// r10 compile failure).
__device__ __forceinline__ float to_vgpr(float x) {
    asm volatile("" : "+v"(x));
    return x;
}

// ---------------------------------------------------------------------------
// fp32 -> bf16 (zero-padded to LDK) + exact fp32 row norms, fused.
// grid = (8192, 3), block = 256.  [proven r5-r7]
// ---------------------------------------------------------------------------
__global__ void convert_kernel(const float* __restrict__ dat,
                               const float* __restrict__ rec,
                               const float* __restrict__ z,
                               unsigned short* __restrict__ dat_bf,
                               unsigned short* __restrict__ rec_bf,
                               unsigned short* __restrict__ z_bf,
                               float* __restrict__ a2d,
                               float* __restrict__ a2r,
                               float* __restrict__ a2z)
{
    const float* X; unsigned short* O; float* N2; int D, LDK;
    if (blockIdx.y == 0)      { X = dat; O = dat_bf; N2 = a2d; D = DDAT; LDK = LDK_D; }
    else if (blockIdx.y == 1) { X = rec; O = rec_bf; N2 = a2r; D = DDAT; LDK = LDK_D; }
    else                      { X = z;   O = z_bf;   N2 = a2z; D = DLAT; LDK = DLAT; }

    const int row = blockIdx.x;
    float s = 0.f;
    for (int k = threadIdx.x; k < LDK; k += 256) {
        float v = (k < D) ? X[(size_t)row * D + k] : 0.f;
        __hip_bfloat16 h = __float2bfloat16(v);
        O[(size_t)row * LDK + k] = *reinterpret_cast<unsigned short*>(&h);
        s += v * v;
    }
    __shared__ float sm[256];
    sm[threadIdx.x] = s;
    __syncthreads();
    for (int off = 128; off > 0; off >>= 1) {
        if (threadIdx.x < off) sm[threadIdx.x] += sm[threadIdx.x + off];
        __syncthreads();
    }
    if (threadIdx.x == 0) N2[row] = sm[0];
}

// ---------------------------------------------------------------------------
// [fast path] Merged triangular MFMA pairwise-phi kernel, REG-STAGED.
// (r9 post-mortem: all global_load_lds pipelines were intermittently racy —
//  r2/r4/r8/r9 failures; reg-staged kernels r0/r3 were deterministic.)
//
// Staging: global_load_dwordx4 -> VGPR -> ds_write_b128. Pipeline, ONE
// barrier/iter, structurally race-free:
//   iter k: {gload tile k+1 -> regs | frag-read buf[p] + MFMA |
//            ds_write buf[p^1] <- regs | barrier}
// ds_writes touch only the buffer nobody reads this iteration; the barrier
// publishes them; global load latency hides under the 16-MFMA phase.
//
// LDS content layout identical to r6/r7 (verified absmax 0.0, 0 bank
// conflicts): write halfS = half ^ ((row>>1)&3), read slot = kg ^ ((lr>>1)&3).
// Supertile + XCD-chunk remap verified r7 (FETCH 837->152 MB).
// ---------------------------------------------------------------------------
__global__ __launch_bounds__(256, 2)
void pair_tri_reg(const unsigned short* __restrict__ cat,  // 16384 x LDK_D
                  const float* __restrict__ n2,            // 16384
                  float alpha, float beta,
                  double* __restrict__ part)               // 3 * NSLOT
{
    const int lin = blockIdx.x;
    const int swz = (lin & 7) * CHUNK + (lin >> 3);   // XCD-chunked bijection
    const int st  = swz >> 6;                         // supertile id (0..135)
    const int blk = swz & 63;                         // slot within supertile

    int sby = 0, rem = st;                            // triangular decode
    while (rem >= NSB - sby) { rem -= NSB - sby; ++sby; }
    const int sbx = sby + rem;

    const int by = sby * SG + (blk >> 3);
    const int bx = sbx * SG + (blk & 7);
    if (by > bx) return;    // idle slot of diagonal supertile (parts pre-zeroed)

    int region; float w;
    if (bx < NBTC / 2)       { region = 0; w = (bx == by) ? 1.f : 2.f; }   // dd
    else if (by >= NBTC / 2) { region = 1; w = (bx == by) ? 1.f : 2.f; }   // rr
    else                     { region = 2; w = 1.f; }                      // dr

    const int t    = threadIdx.x;
    const int lane = t & 63;
    const int wave = t >> 6;
    const int wm = wave >> 1;    // wave row (0..1)
    const int wn = wave & 1;     // wave col (0..1)
    const size_t i0 = (size_t)by * TILE;
    const size_t j0 = (size_t)bx * TILE;

    __shared__ __align__(16) unsigned short As[2][TILE * 32];
    __shared__ __align__(16) unsigned short Bs[2][TILE * 32];

    f32x4 acc[4][4] = {};
    uint4 ra[2], rb[2];          // in-flight staging registers

    // chunk g in [0,512): row = g>>2, k-half = g&3 (8 bf16 = 16B each).
    auto gload = [&](int K0) {
#pragma unroll
        for (int s = 0; s < 2; ++s) {
            const int g   = s * 256 + t;
            const int row = g >> 2;
            const int kb  = K0 + (g & 3) * 8;
            ra[s] = *reinterpret_cast<const uint4*>(&cat[(i0 + row) * LDK_D + kb]);
            rb[s] = *reinterpret_cast<const uint4*>(&cat[(j0 + row) * LDK_D + kb]);
        }
    };
    auto swrite = [&](int P) {
#pragma unroll
        for (int s = 0; s < 2; ++s) {
            const int g     = s * 256 + t;
            const int row   = g >> 2;
            const int halfS = (g & 3) ^ ((row >> 1) & 3);   // swizzled slot
            *reinterpret_cast<uint4*>(&As[P][row * 32 + halfS * 8]) = ra[s];
            *reinterpret_cast<uint4*>(&Bs[P][row * 32 + halfS * 8]) = rb[s];
        }
    };

    // Prologue: tile 0 into buf 0.
    gload(0);
    swrite(0);
    __syncthreads();

    int p = 0;
    for (int k0 = 0; k0 < LDK_D; k0 += 32) {
        const bool nxt = (k0 + 32 < LDK_D);
        if (nxt) gload(k0 + 32);          // issue early; hides under MFMAs

        const int lr   = lane & 15;
        const int kg   = lane >> 4;
        const int slot = kg ^ ((lr >> 1) & 3);   // read-side swizzle
        bf16x8 af[4], bfr[4];
#pragma unroll
        for (int m = 0; m < 4; ++m)
            af[m] = *reinterpret_cast<const bf16x8*>(
                &As[p][(wm * 64 + m * 16 + lr) * 32 + slot * 8]);
#pragma unroll
        for (int n = 0; n < 4; ++n)
            bfr[n] = *reinterpret_cast<const bf16x8*>(
                &Bs[p][(wn * 64 + n * 16 + lr) * 32 + slot * 8]);
#pragma unroll
        for (int m = 0; m < 4; ++m)
#pragma unroll
            for (int n = 0; n < 4; ++n)
                acc[m][n] = __builtin_amdgcn_mfma_f32_16x16x32_bf16(
                    af[m], bfr[n], acc[m][n], 0, 0, 0);

        if (nxt) swrite(p ^ 1);           // other buffer: no reader this iter
        __syncthreads();                  // publish writes; gate next iter
        p ^= 1;
    }

    // Epilogue: C/D layout col = lane&15, row = (lane>>4)*4 + q  [m89/m91]
    const float alpha_v = to_vgpr(alpha);   // constant-bus fix (r10)
    const float beta_v  = to_vgpr(beta);
    float lsum = 0.f;
    const int cr = lane >> 4;
    const int cc = lane & 15;
#pragma unroll
    for (int m = 0; m < 4; ++m) {
#pragma unroll
        for (int n = 0; n < 4; ++n) {
#pragma unroll
            for (int q = 0; q < 4; ++q) {
                const int gi = (int)i0 + wm * 64 + m * 16 + cr * 4 + q;
                const int gj = (int)j0 + wn * 64 + n * 16 + cc;
                float d = n2[gi] + n2[gj] - 2.f * acc[m][n][q];
                d = fmaxf(d, 0.f);
                float x = alpha_v + beta_v * d;
                float r = __frsqrt_rn(x);
                r = r * (1.5f - 0.5f * x * r * r);   // one Newton step
                lsum += r;
            }
        }
    }
    lsum *= w;

    __shared__ float red[256];
    red[t] = lsum;
    __syncthreads();
    for (int off = 128; off > 0; off >>= 1) {
        if (t < off) red[t] += red[t + off];
        __syncthreads();
    }
    if (t == 0) part[(size_t)region * NSLOT + swz] = (double)red[0];
}

// ---------------------------------------------------------------------------
// [fast path, zz] REG-STAGED whole-K kernel (K=64 fits LDS: 2x16KB).
// Swizzle: write halfS = half ^ (row&7); read slot = kgg ^ (lr&7)
// (row&7 == lr&7 for row = wm*64 + m*16 + lr). One barrier total.
// ---------------------------------------------------------------------------
__global__ __launch_bounds__(256, 2)
void pair_zz_reg(const unsigned short* __restrict__ Z,   // 8192 x 64 bf16
                 const float* __restrict__ a2,
                 float alpha, float beta,
                 double* __restrict__ part)              // NBT x NBT
{
    const int bx = blockIdx.x;
    const int by = blockIdx.y;
    const int t  = threadIdx.x;
    if (bx < by) {
        if (t == 0) part[(size_t)by * NBT + bx] = 0.0;
        return;
    }
    const int lane = t & 63;
    const int wave = t >> 6;
    const int wm = wave >> 1;
    const int wn = wave & 1;
    const size_t i0 = (size_t)by * TILE;
    const size_t j0 = (size_t)bx * TILE;

    __shared__ __align__(16) unsigned short As[TILE * 64];
    __shared__ __align__(16) unsigned short Bs[TILE * 64];

    // Stage all 128x64 bf16 per matrix: 1024 x 16B chunks, 4 per thread.
#pragma unroll
    for (int s = 0; s < 4; ++s) {
        const int g    = s * 256 + t;
        const int row  = g >> 3;          // 0..127
        const int half = g & 7;           // 0..7
        const int halfS = half ^ (row & 7);
        uint4 va = *reinterpret_cast<const uint4*>(&Z[(i0 + row) * DLAT + half * 8]);
        uint4 vb = *reinterpret_cast<const uint4*>(&Z[(j0 + row) * DLAT + half * 8]);
        *reinterpret_cast<uint4*>(&As[row * 64 + halfS * 8]) = va;
        *reinterpret_cast<uint4*>(&Bs[row * 64 + halfS * 8]) = vb;
    }
    __syncthreads();

    f32x4 acc[4][4] = {};
    const int lr = lane & 15;
#pragma unroll
    for (int ks = 0; ks < 2; ++ks) {          // two K=32 steps
        const int kgg = ks * 4 + (lane >> 4); // global k-chunk 0..7
        bf16x8 af[4], bfr[4];
#pragma unroll
        for (int m = 0; m < 4; ++m) {
            const int rowA = wm * 64 + m * 16 + lr;
            af[m] = *reinterpret_cast<const bf16x8*>(
                &As[rowA * 64 + (kgg ^ (lr & 7)) * 8]);
        }
#pragma unroll
        for (int n = 0; n < 4; ++n) {
            const int rowB = wn * 64 + n * 16 + lr;
            bfr[n] = *reinterpret_cast<const bf16x8*>(
                &Bs[rowB * 64 + (kgg ^ (lr & 7)) * 8]);
        }
#pragma unroll
        for (int m = 0; m < 4; ++m)
#pragma unroll
            for (int n = 0; n < 4; ++n)
                acc[m][n] = __builtin_amdgcn_mfma_f32_16x16x32_bf16(
                    af[m], bfr[n], acc[m][n], 0, 0, 0);
    }

    const float alpha_v = to_vgpr(alpha);   // constant-bus fix (r10)
    const float beta_v  = to_vgpr(beta);
    float lsum = 0.f;
    const int cr = lane >> 4;
    const int cc = lane & 15;
#pragma unroll
    for (int m = 0; m < 4; ++m) {
#pragma unroll
        for (int n = 0; n < 4; ++n) {
#pragma unroll
            for (int q = 0; q < 4; ++q) {
                const int gi = (int)i0 + wm * 64 + m * 16 + cr * 4 + q;
                const int gj = (int)j0 + wn * 64 + n * 16 + cc;
                float d = a2[gi] + a2[gj] - 2.f * acc[m][n][q];
                d = fmaxf(d, 0.f);
                float x = alpha_v + beta_v * d;
                float r = __frsqrt_rn(x);
                r = r * (1.5f - 0.5f * x * r * r);
                lsum += r;
            }
        }
    }
    if (bx > by) lsum *= 2.f;

    __shared__ float red[256];
    red[t] = lsum;
    __syncthreads();
    for (int off = 128; off > 0; off >>= 1) {
        if (t < off) red[t] += red[t + off];
        __syncthreads();
    }
    if (t == 0) part[(size_t)by * NBT + bx] = (double)red[0];
}

// ---------------------------------------------------------------------------
// [slow path fallback] round-3 verified kernels (+ constant-bus fix).
// ---------------------------------------------------------------------------
__global__ void rownorm_kernel(const float* __restrict__ dat,
                               const float* __restrict__ rec,
                               const float* __restrict__ z,
                               float* __restrict__ o_dat,
                               float* __restrict__ o_rec,
                               float* __restrict__ o_z)
{
    const float* X; float* O; int D;
    if (blockIdx.y == 0)      { X = dat; O = o_dat; D = DDAT; }
    else if (blockIdx.y == 1) { X = rec; O = o_rec; D = DDAT; }
    else                      { X = z;   O = o_z;   D = DLAT; }

    int row = blockIdx.x;
    float s = 0.f;
    for (int k = threadIdx.x; k < D; k += 256) {
        float v = X[(size_t)row * D + k];
        s += v * v;
    }
    __shared__ float sm[256];
    sm[threadIdx.x] = s;
    __syncthreads();
    for (int off = 128; off > 0; off >>= 1) {
        if (threadIdx.x < off) sm[threadIdx.x] += sm[threadIdx.x + off];
        __syncthreads();
    }
    if (threadIdx.x == 0) O[row] = sm[0];
}

__global__ __launch_bounds__(256, 2)
void pair_mfma_kernel(const float* __restrict__ A,
                      const float* __restrict__ B,
                      const float* __restrict__ a2,
                      const float* __restrict__ b2,
                      int D, float alpha, float beta, int sym,
                      double* __restrict__ part)
{
    const int bx = blockIdx.x;
    const int by = blockIdx.y;
    const int t  = threadIdx.x;
    if (sym && bx < by) {
        if (t == 0) part[(size_t)by * NBT + bx] = 0.0;
        return;
    }
    const int lane = t & 63;
    const int wave = t >> 6;
    const int wm = wave >> 1;
    const int wn = wave & 1;
    const int i0 = by * TILE;
    const int j0 = bx * TILE;

    __shared__ __align__(16) unsigned short As[TILE * 32];
    __shared__ __align__(16) unsigned short Bs[TILE * 32];

    f32x4 acc[4][4] = {};

    for (int k0 = 0; k0 < D; k0 += 32) {
        __syncthreads();
#pragma unroll
        for (int s = 0; s < 2; ++s) {
            const int g   = s * 256 + t;
            const int row = g >> 2;
            const int kb  = k0 + (g & 3) * 8;

            float va[8], vb[8];
            const float* srcA = &A[(size_t)(i0 + row) * D + kb];
            const float* srcB = &B[(size_t)(j0 + row) * D + kb];
            if (kb + 8 <= D) {
                float4 a0 = *reinterpret_cast<const float4*>(srcA);
                float4 a1 = *reinterpret_cast<const float4*>(srcA + 4);
                va[0]=a0.x; va[1]=a0.y; va[2]=a0.z; va[3]=a0.w;
                va[4]=a1.x; va[5]=a1.y; va[6]=a1.z; va[7]=a1.w;
                float4 b0 = *reinterpret_cast<const float4*>(srcB);
                float4 b1 = *reinterpret_cast<const float4*>(srcB + 4);
                vb[0]=b0.x; vb[1]=b0.y; vb[2]=b0.z; vb[3]=b0.w;
                vb[4]=b1.x; vb[5]=b1.y; vb[6]=b1.z; vb[7]=b1.w;
            } else {
#pragma unroll
                for (int c = 0; c < 8; ++c) {
                    va[c] = (kb + c < D) ? srcA[c] : 0.f;
                    vb[c] = (kb + c < D) ? srcB[c] : 0.f;
                }
            }
            bf16x8 pa, pb;
#pragma unroll
            for (int c = 0; c < 8; ++c) {
                __hip_bfloat16 ha = __float2bfloat16(va[c]);
                __hip_bfloat16 hb = __float2bfloat16(vb[c]);
                pa[c] = *reinterpret_cast<short*>(&ha);
                pb[c] = *reinterpret_cast<short*>(&hb);
            }
            *reinterpret_cast<bf16x8*>(&As[g * 8]) = pa;
            *reinterpret_cast<bf16x8*>(&Bs[g * 8]) = pb;
        }
        __syncthreads();

        const int lr = lane & 15;
        const int kg = lane >> 4;
        bf16x8 af[4], bfr[4];
#pragma unroll
        for (int m = 0; m < 4; ++m)
            af[m] = *reinterpret_cast<const bf16x8*>(
                &As[(wm * 64 + m * 16 + lr) * 32 + kg * 8]);
#pragma unroll
        for (int n = 0; n < 4; ++n)
            bfr[n] = *reinterpret_cast<const bf16x8*>(
                &Bs[(wn * 64 + n * 16 + lr) * 32 + kg * 8]);
#pragma unroll
        for (int m = 0; m < 4; ++m)
#pragma unroll
            for (int n = 0; n < 4; ++n)
                acc[m][n] = __builtin_amdgcn_mfma_f32_16x16x32_bf16(
                    af[m], bfr[n], acc[m][n], 0, 0, 0);
    }

    const float alpha_v = to_vgpr(alpha);   // constant-bus fix (r10)
    const float beta_v  = to_vgpr(beta);
    float lsum = 0.f;
    const int cr = lane >> 4;
    const int cc = lane & 15;
#pragma unroll
    for (int m = 0; m < 4; ++m) {
#pragma unroll
        for (int n = 0; n < 4; ++n) {
#pragma unroll
            for (int q = 0; q < 4; ++q) {
                const int gi = i0 + wm * 64 + m * 16 + cr * 4 + q;
                const int gj = j0 + wn * 64 + n * 16 + cc;
                float d = a2[gi] + b2[gj] - 2.f * acc[m][n][q];
                d = fmaxf(d, 0.f);
                float x = alpha_v + beta_v * d;
                float r = __frsqrt_rn(x);
                r = r * (1.5f - 0.5f * x * r * r);
                lsum += r;
            }
        }
    }
    if (sym && bx > by) lsum *= 2.f;

    __shared__ float red[256];
    red[t] = lsum;
    __syncthreads();
    for (int off = 128; off > 0; off >>= 1) {
        if (t < off) red[t] += red[t + off];
        __syncthreads();
    }
    if (t == 0) part[(size_t)by * NBT + bx] = (double)red[0];
}

// ---------------------------------------------------------------------------
// Finalize (fast path): 3 region sums over NSLOT + zz over NPARTS + z norms.
// ---------------------------------------------------------------------------
__global__ void finalize_tri(const double* __restrict__ parts3,
                             const double* __restrict__ partsZ,
                             const float* __restrict__ z2,
                             float* __restrict__ out)
{
    const int tid = threadIdx.x;
    double s0 = 0, s1 = 0, s2 = 0, s3 = 0, s4 = 0;
    for (int i = tid; i < NSLOT; i += 256) {
        s0 += parts3[i];
        s1 += parts3[NSLOT + i];
        s2 += parts3[2 * NSLOT + i];
    }
    for (int i = tid; i < NPARTS; i += 256) s3 += partsZ[i];
    for (int i = tid; i < NROWS; i += 256) s4 += (double)z2[i];

    __shared__ double sm[256];
    double tot[5];
    double loc[5] = { s0, s1, s2, s3, s4 };
    for (int j = 0; j < 5; ++j) {
        sm[tid] = loc[j];
        __syncthreads();
        for (int off = 128; off > 0; off >>= 1) {
            if (tid < off) sm[tid] += sm[tid + off];
            __syncthreads();
        }
        tot[j] = sm[0];
        __syncthreads();
    }

    if (tid == 0) {
        const double Nn = (double)NROWS;
        const double n2 = Nn * Nn;
        const double y  = pow(4.0 / (3.0 * Nn), 0.4);

        double A = tot[0] / n2;
        double B = tot[1] / n2;
        double C = tot[2] / n2;
        double T = 1.0 / (2.0 * sqrt(M_PI * y));
        double loss_rec = log(T * (A + B - 2.0 * C));

        double An = tot[3] / n2;
        double B1 = tot[4];
        double Bn = 2.0 / sqrt(y + 0.5 + B1 / 125.0);
        double loss_norm = log(1.0 / sqrt(1.0 + y) + An - Bn);

        out[0] = (float)(loss_rec + loss_norm);
    }
}

// Finalize (slow path): round-3 layout (4 x NPARTS).
__global__ void finalize_kernel(const double* __restrict__ parts,
                                const float* __restrict__ z2,
                                float* __restrict__ out)
{
    const int tid = threadIdx.x;
    double s0 = 0, s1 = 0, s2 = 0, s3 = 0, s4 = 0;
    for (int i = tid; i < NPARTS; i += 256) {
        s0 += parts[i];
        s1 += parts[NPARTS + i];
        s2 += parts[2 * NPARTS + i];
        s3 += parts[3 * NPARTS + i];
    }
    for (int i = tid; i < NROWS; i += 256) s4 += (double)z2[i];

    __shared__ double sm[256];
    double tot[5];
    double loc[5] = { s0, s1, s2, s3, s4 };
    for (int j = 0; j < 5; ++j) {
        sm[tid] = loc[j];
        __syncthreads();
        for (int off = 128; off > 0; off >>= 1) {
            if (tid < off) sm[tid] += sm[tid + off];
            __syncthreads();
        }
        tot[j] = sm[0];
        __syncthreads();
    }

    if (tid == 0) {
        const double Nn = (double)NROWS;
        const double n2 = Nn * Nn;
        const double y  = pow(4.0 / (3.0 * Nn), 0.4);

        double A = tot[0] / n2;
        double B = tot[1] / n2;
        double C = tot[2] / n2;
        double T = 1.0 / (2.0 * sqrt(M_PI * y));
        double loss_rec = log(T * (A + B - 2.0 * C));

        double An = tot[3] / n2;
        double B1 = tot[4];
        double Bn = 2.0 / sqrt(y + 0.5 + B1 / 125.0);
        double loss_norm = log(1.0 / sqrt(1.0 + y) + An - Bn);

        out[0] = (float)(loss_rec + loss_norm);
    }
}

// ---------------------------------------------------------------------------
extern "C" void kernel_launch(void* const* d_in, const int* in_sizes, int n_in,
                              void* d_out, int out_size, void* d_ws, size_t ws_size,
                              hipStream_t stream)
{
    const float* data = (const float*)d_in[0];
    const float* rec  = (const float*)d_in[1];
    const float* z    = (const float*)d_in[2];
    float* out = (float*)d_out;

    // ws layout: [parts (3*NSLOT + NPARTS doubles, >= slow's 4*NPARTS)]
    //            [a2d a2r a2z][dat_bf rec_bf (concat) z_bf]
    const size_t PARTS_DBL = (size_t)3 * NSLOT + NPARTS;   // 30208 doubles
    char* ws = (char*)d_ws;
    double* parts3 = (double*)ws;
    double* partsZ = parts3 + (size_t)3 * NSLOT;
    float*  a2d    = (float*)(parts3 + PARTS_DBL);
    float*  a2r    = a2d + NROWS;     // adjacent: [a2d;a2r] = concat norms
    float*  a2z    = a2r + NROWS;
    unsigned short* dat_bf = (unsigned short*)(a2z + NROWS);
    unsigned short* rec_bf = dat_bf + (size_t)NROWS * LDK_D;  // adjacent: concat
    unsigned short* z_bf   = rec_bf + (size_t)NROWS * LDK_D;

    const size_t base_need = PARTS_DBL * sizeof(double) + 3 * (size_t)NROWS * sizeof(float);
    const size_t full_need = base_need +
        (2 * (size_t)NROWS * LDK_D + (size_t)NROWS * DLAT) * sizeof(unsigned short);
    const bool fast = (ws_size >= full_need);

    const double y = pow(4.0 / (3.0 * (double)NROWS), 0.4);
    const float beta_s = (float)(1.0 / (1565.0 * y));   // 2*DDAT-3 = 1565

    if (fast) {
        (void)hipMemsetAsync(parts3, 0, PARTS_DBL * sizeof(double), stream);
        convert_kernel<<<dim3(NROWS, 3), 256, 0, stream>>>(
            data, rec, z, dat_bf, rec_bf, z_bf, a2d, a2r, a2z);
        // dd + rr + dr in one supertiled triangular launch over concat
        pair_tri_reg<<<NSLOT, 256, 0, stream>>>(
            dat_bf, a2d, 1.0f, beta_s, parts3);
        // normality: z-z (symmetric), phi = rsqrt(y + dist/125)
        pair_zz_reg<<<dim3(NBT, NBT), 256, 0, stream>>>(
            z_bf, a2z, (float)y, 1.0f / 125.0f, partsZ);
        finalize_tri<<<1, 256, 0, stream>>>(parts3, partsZ, a2z, out);
    } else {
        double* parts = parts3;   // slow layout: 4 x NPARTS
        (void)hipMemsetAsync(parts, 0, 4 * (size_t)NPARTS * sizeof(double), stream);
        rownorm_kernel<<<dim3(NROWS, 3), 256, 0, stream>>>(
            data, rec, z, a2d, a2r, a2z);
        dim3 grid(NBT, NBT);
        pair_mfma_kernel<<<grid, 256, 0, stream>>>(
            data, data, a2d, a2d, DDAT, 1.0f, beta_s, 1, parts);
        pair_mfma_kernel<<<grid, 256, 0, stream>>>(
            rec, rec, a2r, a2r, DDAT, 1.0f, beta_s, 1, parts + NPARTS);
        pair_mfma_kernel<<<grid, 256, 0, stream>>>(
            data, rec, a2d, a2r, DDAT, 1.0f, beta_s, 0, parts + 2 * NPARTS);
        pair_mfma_kernel<<<grid, 256, 0, stream>>>(
            z, z, a2z, a2z, DLAT, (float)y, 1.0f / 125.0f, 1, parts + 3 * NPARTS);
        finalize_kernel<<<1, 256, 0, stream>>>(parts, a2z, out);
    }
}

// Round 12
// 338.232 us; speedup vs baseline: 2.9480x; 2.9480x over previous
//
#include <hip/hip_runtime.h>
#include <hip/hip_bf16.h>
#include <math.h>

// Problem constants
#define NROWS 8192
#define DDAT  784
#define LDK_D 800            // padded K (multiple of 32)
#define DLAT  64
#define TILE  128            // output tile per block
#define NBT   64             // zz grid dim: 8192/128
#define NPARTS (NBT * NBT)   // 4096 zz partial slots
#define NBTC  128            // concat rows 16384 / 128
// Supertile decomposition of the 128x128 block triangle:
#define SG    8              // supertile = 8x8 blocks
#define NSB   (NBTC / SG)    // 16 supertiles per dim
#define NST   (NSB * (NSB + 1) / 2)   // 136 supertiles (incl diagonal)
#define NSLOT (NST * SG * SG)         // 8704 launch slots
#define CHUNK (NSLOT / 8)             // 1088 per XCD (exact)

typedef __attribute__((ext_vector_type(8))) short bf16x8;
typedef __attribute__((ext_vector_type(4))) float f32x4;

// Pin a scalar kernel arg into a VGPR (constant-bus fix, r10).
__device__ __forceinline__ float to_vgpr(float x) {
    asm volatile("" : "+v"(x));
    return x;
}

// ---------------------------------------------------------------------------
// fp32 -> bf16 (zero-padded to LDK) + exact fp32 row norms, fused.
// grid = (8192, 3), block = 256.  [proven r5-r7]
// ---------------------------------------------------------------------------
__global__ void convert_kernel(const float* __restrict__ dat,
                               const float* __restrict__ rec,
                               const float* __restrict__ z,
                               unsigned short* __restrict__ dat_bf,
                               unsigned short* __restrict__ rec_bf,
                               unsigned short* __restrict__ z_bf,
                               float* __restrict__ a2d,
                               float* __restrict__ a2r,
                               float* __restrict__ a2z)
{
    const float* X; unsigned short* O; float* N2; int D, LDK;
    if (blockIdx.y == 0)      { X = dat; O = dat_bf; N2 = a2d; D = DDAT; LDK = LDK_D; }
    else if (blockIdx.y == 1) { X = rec; O = rec_bf; N2 = a2r; D = DDAT; LDK = LDK_D; }
    else                      { X = z;   O = z_bf;   N2 = a2z; D = DLAT; LDK = DLAT; }

    const int row = blockIdx.x;
    float s = 0.f;
    for (int k = threadIdx.x; k < LDK; k += 256) {
        float v = (k < D) ? X[(size_t)row * D + k] : 0.f;
        __hip_bfloat16 h = __float2bfloat16(v);
        O[(size_t)row * LDK + k] = *reinterpret_cast<unsigned short*>(&h);
        s += v * v;
    }
    __shared__ float sm[256];
    sm[threadIdx.x] = s;
    __syncthreads();
    for (int off = 128; off > 0; off >>= 1) {
        if (threadIdx.x < off) sm[threadIdx.x] += sm[threadIdx.x + off];
        __syncthreads();
    }
    if (threadIdx.x == 0) N2[row] = sm[0];
}

// ---------------------------------------------------------------------------
// [fast path] Merged triangular MFMA pairwise-phi kernel, REG-STAGED.
// r11 post-mortem: lambda-captured staging arrays were demoted to SCRATCH
// (WRITE_SIZE 2 GB/dispatch, MfmaUtil 9%). This version uses straight-line
// code with NAMED uint4 registers — no arrays, no lambdas, no address-taken
// locals — so staging stays in VGPRs.
//
// Pipeline (r11-proven deterministic), ONE barrier/iter:
//   iter k: {gload tile k+1 -> regs | frag-read buf[p] + MFMA |
//            ds_write buf[p^1] <- regs | barrier}
// LDS swizzle verified r6/r7 (0 bank conflicts): write halfS = half ^
// ((row>>1)&3); read slot = kg ^ ((lr>>1)&3).
// Supertile + XCD-chunk remap verified r7 (FETCH 837->152 MB).
// ---------------------------------------------------------------------------
__global__ __launch_bounds__(256, 2)
void pair_tri_reg(const unsigned short* __restrict__ cat,  // 16384 x LDK_D
                  const float* __restrict__ n2,            // 16384
                  float alpha, float beta,
                  double* __restrict__ part)               // 3 * NSLOT
{
    const int lin = blockIdx.x;
    const int swz = (lin & 7) * CHUNK + (lin >> 3);   // XCD-chunked bijection
    const int st  = swz >> 6;                         // supertile id (0..135)
    const int blk = swz & 63;                         // slot within supertile

    int sby = 0, rem = st;                            // triangular decode
    while (rem >= NSB - sby) { rem -= NSB - sby; ++sby; }
    const int sbx = sby + rem;

    const int by = sby * SG + (blk >> 3);
    const int bx = sbx * SG + (blk & 7);
    if (by > bx) return;    // idle slot of diagonal supertile (parts pre-zeroed)

    int region; float w;
    if (bx < NBTC / 2)       { region = 0; w = (bx == by) ? 1.f : 2.f; }   // dd
    else if (by >= NBTC / 2) { region = 1; w = (bx == by) ? 1.f : 2.f; }   // rr
    else                     { region = 2; w = 1.f; }                      // dr

    const int t    = threadIdx.x;
    const int lane = t & 63;
    const int wave = t >> 6;
    const int wm = wave >> 1;    // wave row (0..1)
    const int wn = wave & 1;     // wave col (0..1)
    const size_t i0 = (size_t)by * TILE;
    const size_t j0 = (size_t)bx * TILE;

    __shared__ __align__(16) unsigned short As[2][TILE * 32];
    __shared__ __align__(16) unsigned short Bs[2][TILE * 32];

    // Per-thread staging geometry (hoisted): chunk s=0 -> row r0 = t>>2,
    // chunk s=1 -> row r1 = 64 + (t>>2); k-offset kbo = (t&3)*8.
    // Swizzled LDS slot: halfS = (t&3) ^ ((row>>1)&3); note
    // ((r1>>1)&3) == ((r0>>1)&3) because r1-r0 = 64, so one halfS serves both.
    const int r0  = t >> 2;
    const int r1  = 64 + r0;
    const int kbo = (t & 3) * 8;
    const int halfS = (t & 3) ^ ((r0 >> 1) & 3);
    const int ldsOff0 = r0 * 32 + halfS * 8;   // shorts
    const int ldsOff1 = r1 * 32 + halfS * 8;
    const unsigned short* gA0 = &cat[(i0 + r0) * LDK_D + kbo];
    const unsigned short* gA1 = &cat[(i0 + r1) * LDK_D + kbo];
    const unsigned short* gB0 = &cat[(j0 + r0) * LDK_D + kbo];
    const unsigned short* gB1 = &cat[(j0 + r1) * LDK_D + kbo];

    f32x4 acc[4][4] = {};
    uint4 ra0, ra1, rb0, rb1;    // named staging registers (stay in VGPRs)

    // Prologue: tile 0 into buf 0.
    ra0 = *reinterpret_cast<const uint4*>(gA0);
    ra1 = *reinterpret_cast<const uint4*>(gA1);
    rb0 = *reinterpret_cast<const uint4*>(gB0);
    rb1 = *reinterpret_cast<const uint4*>(gB1);
    *reinterpret_cast<uint4*>(&As[0][ldsOff0]) = ra0;
    *reinterpret_cast<uint4*>(&As[0][ldsOff1]) = ra1;
    *reinterpret_cast<uint4*>(&Bs[0][ldsOff0]) = rb0;
    *reinterpret_cast<uint4*>(&Bs[0][ldsOff1]) = rb1;
    __syncthreads();

    const int lr   = lane & 15;
    const int kg   = lane >> 4;
    const int slot = kg ^ ((lr >> 1) & 3);   // read-side swizzle

    int p = 0;
    for (int k0 = 0; k0 < LDK_D; k0 += 32) {
        const bool nxt = (k0 + 32 < LDK_D);
        if (nxt) {                       // issue early; hides under MFMAs
            const int ko = k0 + 32;
            ra0 = *reinterpret_cast<const uint4*>(gA0 + ko);
            ra1 = *reinterpret_cast<const uint4*>(gA1 + ko);
            rb0 = *reinterpret_cast<const uint4*>(gB0 + ko);
            rb1 = *reinterpret_cast<const uint4*>(gB1 + ko);
        }

        bf16x8 af[4], bfr[4];
#pragma unroll
        for (int m = 0; m < 4; ++m)
            af[m] = *reinterpret_cast<const bf16x8*>(
                &As[p][(wm * 64 + m * 16 + lr) * 32 + slot * 8]);
#pragma unroll
        for (int n = 0; n < 4; ++n)
            bfr[n] = *reinterpret_cast<const bf16x8*>(
                &Bs[p][(wn * 64 + n * 16 + lr) * 32 + slot * 8]);
#pragma unroll
        for (int m = 0; m < 4; ++m)
#pragma unroll
            for (int n = 0; n < 4; ++n)
                acc[m][n] = __builtin_amdgcn_mfma_f32_16x16x32_bf16(
                    af[m], bfr[n], acc[m][n], 0, 0, 0);

        if (nxt) {                       // other buffer: no reader this iter
            const int q = p ^ 1;
            *reinterpret_cast<uint4*>(&As[q][ldsOff0]) = ra0;
            *reinterpret_cast<uint4*>(&As[q][ldsOff1]) = ra1;
            *reinterpret_cast<uint4*>(&Bs[q][ldsOff0]) = rb0;
            *reinterpret_cast<uint4*>(&Bs[q][ldsOff1]) = rb1;
        }
        __syncthreads();                 // publish writes; gate next iter
        p ^= 1;
    }

    // Epilogue: C/D layout col = lane&15, row = (lane>>4)*4 + q  [m89/m91]
    const float alpha_v = to_vgpr(alpha);
    const float beta_v  = to_vgpr(beta);
    float lsum = 0.f;
    const int cr = lane >> 4;
    const int cc = lane & 15;
#pragma unroll
    for (int m = 0; m < 4; ++m) {
#pragma unroll
        for (int n = 0; n < 4; ++n) {
#pragma unroll
            for (int q = 0; q < 4; ++q) {
                const int gi = (int)i0 + wm * 64 + m * 16 + cr * 4 + q;
                const int gj = (int)j0 + wn * 64 + n * 16 + cc;
                float d = n2[gi] + n2[gj] - 2.f * acc[m][n][q];
                d = fmaxf(d, 0.f);
                float x = alpha_v + beta_v * d;
                float r = __frsqrt_rn(x);
                r = r * (1.5f - 0.5f * x * r * r);   // one Newton step
                lsum += r;
            }
        }
    }
    lsum *= w;

    __shared__ float red[256];
    red[t] = lsum;
    __syncthreads();
    for (int off = 128; off > 0; off >>= 1) {
        if (t < off) red[t] += red[t + off];
        __syncthreads();
    }
    if (t == 0) part[(size_t)region * NSLOT + swz] = (double)red[0];
}

// ---------------------------------------------------------------------------
// [fast path, zz] REG-STAGED whole-K kernel (K=64 fits LDS: 2x16KB).
// Straight-line staging (no arrays). One barrier total.  [r11-proven]
// ---------------------------------------------------------------------------
__global__ __launch_bounds__(256, 2)
void pair_zz_reg(const unsigned short* __restrict__ Z,   // 8192 x 64 bf16
                 const float* __restrict__ a2,
                 float alpha, float beta,
                 double* __restrict__ part)              // NBT x NBT
{
    const int bx = blockIdx.x;
    const int by = blockIdx.y;
    const int t  = threadIdx.x;
    if (bx < by) {
        if (t == 0) part[(size_t)by * NBT + bx] = 0.0;
        return;
    }
    const int lane = t & 63;
    const int wave = t >> 6;
    const int wm = wave >> 1;
    const int wn = wave & 1;
    const size_t i0 = (size_t)by * TILE;
    const size_t j0 = (size_t)bx * TILE;

    __shared__ __align__(16) unsigned short As[TILE * 64];
    __shared__ __align__(16) unsigned short Bs[TILE * 64];

    // Stage all 128x64 bf16 per matrix: 1024 x 16B chunks, 4 per thread.
#pragma unroll
    for (int s = 0; s < 4; ++s) {
        const int g    = s * 256 + t;
        const int row  = g >> 3;          // 0..127
        const int half = g & 7;           // 0..7
        const int halfS = half ^ (row & 7);
        uint4 va = *reinterpret_cast<const uint4*>(&Z[(i0 + row) * DLAT + half * 8]);
        uint4 vb = *reinterpret_cast<const uint4*>(&Z[(j0 + row) * DLAT + half * 8]);
        *reinterpret_cast<uint4*>(&As[row * 64 + halfS * 8]) = va;
        *reinterpret_cast<uint4*>(&Bs[row * 64 + halfS * 8]) = vb;
    }
    __syncthreads();

    f32x4 acc[4][4] = {};
    const int lr = lane & 15;
#pragma unroll
    for (int ks = 0; ks < 2; ++ks) {          // two K=32 steps
        const int kgg = ks * 4 + (lane >> 4); // global k-chunk 0..7
        bf16x8 af[4], bfr[4];
#pragma unroll
        for (int m = 0; m < 4; ++m) {
            const int rowA = wm * 64 + m * 16 + lr;
            af[m] = *reinterpret_cast<const bf16x8*>(
                &As[rowA * 64 + (kgg ^ (lr & 7)) * 8]);
        }
#pragma unroll
        for (int n = 0; n < 4; ++n) {
            const int rowB = wn * 64 + n * 16 + lr;
            bfr[n] = *reinterpret_cast<const bf16x8*>(
                &Bs[rowB * 64 + (kgg ^ (lr & 7)) * 8]);
        }
#pragma unroll
        for (int m = 0; m < 4; ++m)
#pragma unroll
            for (int n = 0; n < 4; ++n)
                acc[m][n] = __builtin_amdgcn_mfma_f32_16x16x32_bf16(
                    af[m], bfr[n], acc[m][n], 0, 0, 0);
    }

    const float alpha_v = to_vgpr(alpha);
    const float beta_v  = to_vgpr(beta);
    float lsum = 0.f;
    const int cr = lane >> 4;
    const int cc = lane & 15;
#pragma unroll
    for (int m = 0; m < 4; ++m) {
#pragma unroll
        for (int n = 0; n < 4; ++n) {
#pragma unroll
            for (int q = 0; q < 4; ++q) {
                const int gi = (int)i0 + wm * 64 + m * 16 + cr * 4 + q;
                const int gj = (int)j0 + wn * 64 + n * 16 + cc;
                float d = a2[gi] + a2[gj] - 2.f * acc[m][n][q];
                d = fmaxf(d, 0.f);
                float x = alpha_v + beta_v * d;
                float r = __frsqrt_rn(x);
                r = r * (1.5f - 0.5f * x * r * r);
                lsum += r;
            }
        }
    }
    if (bx > by) lsum *= 2.f;

    __shared__ float red[256];
    red[t] = lsum;
    __syncthreads();
    for (int off = 128; off > 0; off >>= 1) {
        if (t < off) red[t] += red[t + off];
        __syncthreads();
    }
    if (t == 0) part[(size_t)by * NBT + bx] = (double)red[0];
}

// ---------------------------------------------------------------------------
// [slow path fallback] round-3 verified kernels (+ constant-bus fix).
// ---------------------------------------------------------------------------
__global__ void rownorm_kernel(const float* __restrict__ dat,
                               const float* __restrict__ rec,
                               const float* __restrict__ z,
                               float* __restrict__ o_dat,
                               float* __restrict__ o_rec,
                               float* __restrict__ o_z)
{
    const float* X; float* O; int D;
    if (blockIdx.y == 0)      { X = dat; O = o_dat; D = DDAT; }
    else if (blockIdx.y == 1) { X = rec; O = o_rec; D = DDAT; }
    else                      { X = z;   O = o_z;   D = DLAT; }

    int row = blockIdx.x;
    float s = 0.f;
    for (int k = threadIdx.x; k < D; k += 256) {
        float v = X[(size_t)row * D + k];
        s += v * v;
    }
    __shared__ float sm[256];
    sm[threadIdx.x] = s;
    __syncthreads();
    for (int off = 128; off > 0; off >>= 1) {
        if (threadIdx.x < off) sm[threadIdx.x] += sm[threadIdx.x + off];
        __syncthreads();
    }
    if (threadIdx.x == 0) O[row] = sm[0];
}

__global__ __launch_bounds__(256, 2)
void pair_mfma_kernel(const float* __restrict__ A,
                      const float* __restrict__ B,
                      const float* __restrict__ a2,
                      const float* __restrict__ b2,
                      int D, float alpha, float beta, int sym,
                      double* __restrict__ part)
{
    const int bx = blockIdx.x;
    const int by = blockIdx.y;
    const int t  = threadIdx.x;
    if (sym && bx < by) {
        if (t == 0) part[(size_t)by * NBT + bx] = 0.0;
        return;
    }
    const int lane = t & 63;
    const int wave = t >> 6;
    const int wm = wave >> 1;
    const int wn = wave & 1;
    const int i0 = by * TILE;
    const int j0 = bx * TILE;

    __shared__ __align__(16) unsigned short As[TILE * 32];
    __shared__ __align__(16) unsigned short Bs[TILE * 32];

    f32x4 acc[4][4] = {};

    for (int k0 = 0; k0 < D; k0 += 32) {
        __syncthreads();
#pragma unroll
        for (int s = 0; s < 2; ++s) {
            const int g   = s * 256 + t;
            const int row = g >> 2;
            const int kb  = k0 + (g & 3) * 8;

            float va[8], vb[8];
            const float* srcA = &A[(size_t)(i0 + row) * D + kb];
            const float* srcB = &B[(size_t)(j0 + row) * D + kb];
            if (kb + 8 <= D) {
                float4 a0 = *reinterpret_cast<const float4*>(srcA);
                float4 a1 = *reinterpret_cast<const float4*>(srcA + 4);
                va[0]=a0.x; va[1]=a0.y; va[2]=a0.z; va[3]=a0.w;
                va[4]=a1.x; va[5]=a1.y; va[6]=a1.z; va[7]=a1.w;
                float4 b0 = *reinterpret_cast<const float4*>(srcB);
                float4 b1 = *reinterpret_cast<const float4*>(srcB + 4);
                vb[0]=b0.x; vb[1]=b0.y; vb[2]=b0.z; vb[3]=b0.w;
                vb[4]=b1.x; vb[5]=b1.y; vb[6]=b1.z; vb[7]=b1.w;
            } else {
#pragma unroll
                for (int c = 0; c < 8; ++c) {
                    va[c] = (kb + c < D) ? srcA[c] : 0.f;
                    vb[c] = (kb + c < D) ? srcB[c] : 0.f;
                }
            }
            bf16x8 pa, pb;
#pragma unroll
            for (int c = 0; c < 8; ++c) {
                __hip_bfloat16 ha = __float2bfloat16(va[c]);
                __hip_bfloat16 hb = __float2bfloat16(vb[c]);
                pa[c] = *reinterpret_cast<short*>(&ha);
                pb[c] = *reinterpret_cast<short*>(&hb);
            }
            *reinterpret_cast<bf16x8*>(&As[g * 8]) = pa;
            *reinterpret_cast<bf16x8*>(&Bs[g * 8]) = pb;
        }
        __syncthreads();

        const int lr = lane & 15;
        const int kg = lane >> 4;
        bf16x8 af[4], bfr[4];
#pragma unroll
        for (int m = 0; m < 4; ++m)
            af[m] = *reinterpret_cast<const bf16x8*>(
                &As[(wm * 64 + m * 16 + lr) * 32 + kg * 8]);
#pragma unroll
        for (int n = 0; n < 4; ++n)
            bfr[n] = *reinterpret_cast<const bf16x8*>(
                &Bs[(wn * 64 + n * 16 + lr) * 32 + kg * 8]);
#pragma unroll
        for (int m = 0; m < 4; ++m)
#pragma unroll
            for (int n = 0; n < 4; ++n)
                acc[m][n] = __builtin_amdgcn_mfma_f32_16x16x32_bf16(
                    af[m], bfr[n], acc[m][n], 0, 0, 0);
    }

    const float alpha_v = to_vgpr(alpha);
    const float beta_v  = to_vgpr(beta);
    float lsum = 0.f;
    const int cr = lane >> 4;
    const int cc = lane & 15;
#pragma unroll
    for (int m = 0; m < 4; ++m) {
#pragma unroll
        for (int n = 0; n < 4; ++n) {
#pragma unroll
            for (int q = 0; q < 4; ++q) {
                const int gi = i0 + wm * 64 + m * 16 + cr * 4 + q;
                const int gj = j0 + wn * 64 + n * 16 + cc;
                float d = a2[gi] + b2[gj] - 2.f * acc[m][n][q];
                d = fmaxf(d, 0.f);
                float x = alpha_v + beta_v * d;
                float r = __frsqrt_rn(x);
                r = r * (1.5f - 0.5f * x * r * r);
                lsum += r;
            }
        }
    }
    if (sym && bx > by) lsum *= 2.f;

    __shared__ float red[256];
    red[t] = lsum;
    __syncthreads();
    for (int off = 128; off > 0; off >>= 1) {
        if (t < off) red[t] += red[t + off];
        __syncthreads();
    }
    if (t == 0) part[(size_t)by * NBT + bx] = (double)red[0];
}

// ---------------------------------------------------------------------------
// Finalize (fast path): 3 region sums over NSLOT + zz over NPARTS + z norms.
// ---------------------------------------------------------------------------
__global__ void finalize_tri(const double* __restrict__ parts3,
                             const double* __restrict__ partsZ,
                             const float* __restrict__ z2,
                             float* __restrict__ out)
{
    const int tid = threadIdx.x;
    double s0 = 0, s1 = 0, s2 = 0, s3 = 0, s4 = 0;
    for (int i = tid; i < NSLOT; i += 256) {
        s0 += parts3[i];
        s1 += parts3[NSLOT + i];
        s2 += parts3[2 * NSLOT + i];
    }
    for (int i = tid; i < NPARTS; i += 256) s3 += partsZ[i];
    for (int i = tid; i < NROWS; i += 256) s4 += (double)z2[i];

    __shared__ double sm[256];
    double tot[5];
    double loc[5] = { s0, s1, s2, s3, s4 };
    for (int j = 0; j < 5; ++j) {
        sm[tid] = loc[j];
        __syncthreads();
        for (int off = 128; off > 0; off >>= 1) {
            if (tid < off) sm[tid] += sm[tid + off];
            __syncthreads();
        }
        tot[j] = sm[0];
        __syncthreads();
    }

    if (tid == 0) {
        const double Nn = (double)NROWS;
        const double n2 = Nn * Nn;
        const double y  = pow(4.0 / (3.0 * Nn), 0.4);

        double A = tot[0] / n2;
        double B = tot[1] / n2;
        double C = tot[2] / n2;
        double T = 1.0 / (2.0 * sqrt(M_PI * y));
        double loss_rec = log(T * (A + B - 2.0 * C));

        double An = tot[3] / n2;
        double B1 = tot[4];
        double Bn = 2.0 / sqrt(y + 0.5 + B1 / 125.0);
        double loss_norm = log(1.0 / sqrt(1.0 + y) + An - Bn);

        out[0] = (float)(loss_rec + loss_norm);
    }
}

// Finalize (slow path): round-3 layout (4 x NPARTS).
__global__ void finalize_kernel(const double* __restrict__ parts,
                                const float* __restrict__ z2,
                                float* __restrict__ out)
{
    const int tid = threadIdx.x;
    double s0 = 0, s1 = 0, s2 = 0, s3 = 0, s4 = 0;
    for (int i = tid; i < NPARTS; i += 256) {
        s0 += parts[i];
        s1 += parts[NPARTS + i];
        s2 += parts[2 * NPARTS + i];
        s3 += parts[3 * NPARTS + i];
    }
    for (int i = tid; i < NROWS; i += 256) s4 += (double)z2[i];

    __shared__ double sm[256];
    double tot[5];
    double loc[5] = { s0, s1, s2, s3, s4 };
    for (int j = 0; j < 5; ++j) {
        sm[tid] = loc[j];
        __syncthreads();
        for (int off = 128; off > 0; off >>= 1) {
            if (tid < off) sm[tid] += sm[tid + off];
            __syncthreads();
        }
        tot[j] = sm[0];
        __syncthreads();
    }

    if (tid == 0) {
        const double Nn = (double)NROWS;
        const double n2 = Nn * Nn;
        const double y  = pow(4.0 / (3.0 * Nn), 0.4);

        double A = tot[0] / n2;
        double B = tot[1] / n2;
        double C = tot[2] / n2;
        double T = 1.0 / (2.0 * sqrt(M_PI * y));
        double loss_rec = log(T * (A + B - 2.0 * C));

        double An = tot[3] / n2;
        double B1 = tot[4];
        double Bn = 2.0 / sqrt(y + 0.5 + B1 / 125.0);
        double loss_norm = log(1.0 / sqrt(1.0 + y) + An - Bn);

        out[0] = (float)(loss_rec + loss_norm);
    }
}

// ---------------------------------------------------------------------------
extern "C" void kernel_launch(void* const* d_in, const int* in_sizes, int n_in,
                              void* d_out, int out_size, void* d_ws, size_t ws_size,
                              hipStream_t stream)
{
    const float* data = (const float*)d_in[0];
    const float* rec  = (const float*)d_in[1];
    const float* z    = (const float*)d_in[2];
    float* out = (float*)d_out;

    // ws layout: [parts (3*NSLOT + NPARTS doubles, >= slow's 4*NPARTS)]
    //            [a2d a2r a2z][dat_bf rec_bf (concat) z_bf]
    const size_t PARTS_DBL = (size_t)3 * NSLOT + NPARTS;   // 30208 doubles
    char* ws = (char*)d_ws;
    double* parts3 = (double*)ws;
    double* partsZ = parts3 + (size_t)3 * NSLOT;
    float*  a2d    = (float*)(parts3 + PARTS_DBL);
    float*  a2r    = a2d + NROWS;     // adjacent: [a2d;a2r] = concat norms
    float*  a2z    = a2r + NROWS;
    unsigned short* dat_bf = (unsigned short*)(a2z + NROWS);
    unsigned short* rec_bf = dat_bf + (size_t)NROWS * LDK_D;  // adjacent: concat
    unsigned short* z_bf   = rec_bf + (size_t)NROWS * LDK_D;

    const size_t base_need = PARTS_DBL * sizeof(double) + 3 * (size_t)NROWS * sizeof(float);
    const size_t full_need = base_need +
        (2 * (size_t)NROWS * LDK_D + (size_t)NROWS * DLAT) * sizeof(unsigned short);
    const bool fast = (ws_size >= full_need);

    const double y = pow(4.0 / (3.0 * (double)NROWS), 0.4);
    const float beta_s = (float)(1.0 / (1565.0 * y));   // 2*DDAT-3 = 1565

    if (fast) {
        (void)hipMemsetAsync(parts3, 0, PARTS_DBL * sizeof(double), stream);
        convert_kernel<<<dim3(NROWS, 3), 256, 0, stream>>>(
            data, rec, z, dat_bf, rec_bf, z_bf, a2d, a2r, a2z);
        // dd + rr + dr in one supertiled triangular launch over concat
        pair_tri_reg<<<NSLOT, 256, 0, stream>>>(
            dat_bf, a2d, 1.0f, beta_s, parts3);
        // normality: z-z (symmetric), phi = rsqrt(y + dist/125)
        pair_zz_reg<<<dim3(NBT, NBT), 256, 0, stream>>>(
            z_bf, a2z, (float)y, 1.0f / 125.0f, partsZ);
        finalize_tri<<<1, 256, 0, stream>>>(parts3, partsZ, a2z, out);
    } else {
        double* parts = parts3;   // slow layout: 4 x NPARTS
        (void)hipMemsetAsync(parts, 0, 4 * (size_t)NPARTS * sizeof(double), stream);
        rownorm_kernel<<<dim3(NROWS, 3), 256, 0, stream>>>(
            data, rec, z, a2d, a2r, a2z);
        dim3 grid(NBT, NBT);
        pair_mfma_kernel<<<grid, 256, 0, stream>>>(
            data, data, a2d, a2d, DDAT, 1.0f, beta_s, 1, parts);
        pair_mfma_kernel<<<grid, 256, 0, stream>>>(
            rec, rec, a2r, a2r, DDAT, 1.0f, beta_s, 1, parts + NPARTS);
        pair_mfma_kernel<<<grid, 256, 0, stream>>>(
            data, rec, a2d, a2r, DDAT, 1.0f, beta_s, 0, parts + 2 * NPARTS);
        pair_mfma_kernel<<<grid, 256, 0, stream>>>(
            z, z, a2z, a2z, DLAT, (float)y, 1.0f / 125.0f, 1, parts + 3 * NPARTS);
        finalize_kernel<<<1, 256, 0, stream>>>(parts, a2z, out);
    }
}

// Round 13
// 322.289 us; speedup vs baseline: 3.0938x; 1.0495x over previous
//
#include <hip/hip_runtime.h>
#include <hip/hip_bf16.h>
#include <math.h>

// Problem constants
#define NROWS 8192
#define DDAT  784
#define LDK_D 800            // padded K (multiple of 32)
#define DLAT  64
#define TILE  128            // output tile per block
#define NBT   64             // zz grid dim: 8192/128
#define NPARTS (NBT * NBT)   // 4096 zz partial slots
#define NBTC  128            // concat rows 16384 / 128
// Supertile decomposition of the 128x128 block triangle:
#define SG    8              // supertile = 8x8 blocks
#define NSB   (NBTC / SG)    // 16 supertiles per dim
#define NST   (NSB * (NSB + 1) / 2)   // 136 supertiles (incl diagonal)
#define NSLOT (NST * SG * SG)         // 8704 launch slots
#define CHUNK (NSLOT / 8)             // 1088 per XCD (exact)

typedef __attribute__((ext_vector_type(8))) short bf16x8;
typedef __attribute__((ext_vector_type(4))) float f32x4;

// Pin a scalar kernel arg into a VGPR (constant-bus fix, r10).
__device__ __forceinline__ float to_vgpr(float x) {
    asm volatile("" : "+v"(x));
    return x;
}

// ---------------------------------------------------------------------------
// fp32 -> bf16 (zero-padded to LDK) + exact fp32 row norms, fused.
// grid = (8192, 3), block = 256.  [proven r5-r7]
// ---------------------------------------------------------------------------
__global__ void convert_kernel(const float* __restrict__ dat,
                               const float* __restrict__ rec,
                               const float* __restrict__ z,
                               unsigned short* __restrict__ dat_bf,
                               unsigned short* __restrict__ rec_bf,
                               unsigned short* __restrict__ z_bf,
                               float* __restrict__ a2d,
                               float* __restrict__ a2r,
                               float* __restrict__ a2z)
{
    const float* X; unsigned short* O; float* N2; int D, LDK;
    if (blockIdx.y == 0)      { X = dat; O = dat_bf; N2 = a2d; D = DDAT; LDK = LDK_D; }
    else if (blockIdx.y == 1) { X = rec; O = rec_bf; N2 = a2r; D = DDAT; LDK = LDK_D; }
    else                      { X = z;   O = z_bf;   N2 = a2z; D = DLAT; LDK = DLAT; }

    const int row = blockIdx.x;
    float s = 0.f;
    for (int k = threadIdx.x; k < LDK; k += 256) {
        float v = (k < D) ? X[(size_t)row * D + k] : 0.f;
        __hip_bfloat16 h = __float2bfloat16(v);
        O[(size_t)row * LDK + k] = *reinterpret_cast<unsigned short*>(&h);
        s += v * v;
    }
    __shared__ float sm[256];
    sm[threadIdx.x] = s;
    __syncthreads();
    for (int off = 128; off > 0; off >>= 1) {
        if (threadIdx.x < off) sm[threadIdx.x] += sm[threadIdx.x + off];
        __syncthreads();
    }
    if (threadIdx.x == 0) N2[row] = sm[0];
}

// ---------------------------------------------------------------------------
// [fast path] Merged triangular MFMA pairwise-phi kernel, REG-STAGED.
// r12 verified: WRITE_SIZE 67 KB (no scratch), 0 bank conflicts, absmax 0.0,
// deterministic. Correctness is STRUCTURAL (plain ds_write + buffer parity +
// __syncthreads), so launch_bounds changes cannot introduce races (unlike the
// r8 gload_lds pipeline).
//
// launch_bounds(256,4): r12 ran at 31.6% occupancy (~2.5 blocks/CU) under
// (256,2); LDS 33.8KB allows 4 blocks/CU and VGPR 72 < 128 cap. Resident-
// block overlap is what hides the per-iter barrier drain [m114].
//
// Pipeline, ONE barrier/iter:
//   iter k: {gload tile k+1 -> named regs | frag-read buf[p] + MFMA |
//            ds_write buf[p^1] | barrier}
// LDS swizzle verified r6/r7: write halfS = half ^ ((row>>1)&3);
// read slot = kg ^ ((lr>>1)&3). Supertile + XCD-chunk remap verified r7.
// ---------------------------------------------------------------------------
__global__ __launch_bounds__(256, 4)
void pair_tri_reg(const unsigned short* __restrict__ cat,  // 16384 x LDK_D
                  const float* __restrict__ n2,            // 16384
                  float alpha, float beta,
                  double* __restrict__ part)               // 3 * NSLOT
{
    const int lin = blockIdx.x;
    const int swz = (lin & 7) * CHUNK + (lin >> 3);   // XCD-chunked bijection
    const int st  = swz >> 6;                         // supertile id (0..135)
    const int blk = swz & 63;                         // slot within supertile

    int sby = 0, rem = st;                            // triangular decode
    while (rem >= NSB - sby) { rem -= NSB - sby; ++sby; }
    const int sbx = sby + rem;

    const int by = sby * SG + (blk >> 3);
    const int bx = sbx * SG + (blk & 7);
    if (by > bx) return;    // idle slot of diagonal supertile (parts pre-zeroed)

    int region; float w;
    if (bx < NBTC / 2)       { region = 0; w = (bx == by) ? 1.f : 2.f; }   // dd
    else if (by >= NBTC / 2) { region = 1; w = (bx == by) ? 1.f : 2.f; }   // rr
    else                     { region = 2; w = 1.f; }                      // dr

    const int t    = threadIdx.x;
    const int lane = t & 63;
    const int wave = t >> 6;
    const int wm = wave >> 1;    // wave row (0..1)
    const int wn = wave & 1;     // wave col (0..1)
    const size_t i0 = (size_t)by * TILE;
    const size_t j0 = (size_t)bx * TILE;

    __shared__ __align__(16) unsigned short As[2][TILE * 32];
    __shared__ __align__(16) unsigned short Bs[2][TILE * 32];

    // Per-thread staging geometry (hoisted): chunk s=0 -> row r0 = t>>2,
    // chunk s=1 -> row r1 = 64 + r0; k-offset kbo = (t&3)*8.
    // halfS identical for r0/r1 since r1-r0 = 64.
    const int r0  = t >> 2;
    const int r1  = 64 + r0;
    const int kbo = (t & 3) * 8;
    const int halfS = (t & 3) ^ ((r0 >> 1) & 3);
    const int ldsOff0 = r0 * 32 + halfS * 8;   // shorts
    const int ldsOff1 = r1 * 32 + halfS * 8;
    const unsigned short* gA0 = &cat[(i0 + r0) * LDK_D + kbo];
    const unsigned short* gA1 = &cat[(i0 + r1) * LDK_D + kbo];
    const unsigned short* gB0 = &cat[(j0 + r0) * LDK_D + kbo];
    const unsigned short* gB1 = &cat[(j0 + r1) * LDK_D + kbo];

    f32x4 acc[4][4] = {};
    uint4 ra0, ra1, rb0, rb1;    // named staging registers (stay in VGPRs)

    // Prologue: tile 0 into buf 0.
    ra0 = *reinterpret_cast<const uint4*>(gA0);
    ra1 = *reinterpret_cast<const uint4*>(gA1);
    rb0 = *reinterpret_cast<const uint4*>(gB0);
    rb1 = *reinterpret_cast<const uint4*>(gB1);
    *reinterpret_cast<uint4*>(&As[0][ldsOff0]) = ra0;
    *reinterpret_cast<uint4*>(&As[0][ldsOff1]) = ra1;
    *reinterpret_cast<uint4*>(&Bs[0][ldsOff0]) = rb0;
    *reinterpret_cast<uint4*>(&Bs[0][ldsOff1]) = rb1;
    __syncthreads();

    const int lr   = lane & 15;
    const int kg   = lane >> 4;
    const int slot = kg ^ ((lr >> 1) & 3);   // read-side swizzle

    int p = 0;
    for (int k0 = 0; k0 < LDK_D; k0 += 32) {
        const bool nxt = (k0 + 32 < LDK_D);
        if (nxt) {                       // issue early; hides under MFMAs
            const int ko = k0 + 32;
            ra0 = *reinterpret_cast<const uint4*>(gA0 + ko);
            ra1 = *reinterpret_cast<const uint4*>(gA1 + ko);
            rb0 = *reinterpret_cast<const uint4*>(gB0 + ko);
            rb1 = *reinterpret_cast<const uint4*>(gB1 + ko);
        }

        bf16x8 af[4], bfr[4];
#pragma unroll
        for (int m = 0; m < 4; ++m)
            af[m] = *reinterpret_cast<const bf16x8*>(
                &As[p][(wm * 64 + m * 16 + lr) * 32 + slot * 8]);
#pragma unroll
        for (int n = 0; n < 4; ++n)
            bfr[n] = *reinterpret_cast<const bf16x8*>(
                &Bs[p][(wn * 64 + n * 16 + lr) * 32 + slot * 8]);
#pragma unroll
        for (int m = 0; m < 4; ++m)
#pragma unroll
            for (int n = 0; n < 4; ++n)
                acc[m][n] = __builtin_amdgcn_mfma_f32_16x16x32_bf16(
                    af[m], bfr[n], acc[m][n], 0, 0, 0);

        if (nxt) {                       // other buffer: no reader this iter
            const int q = p ^ 1;
            *reinterpret_cast<uint4*>(&As[q][ldsOff0]) = ra0;
            *reinterpret_cast<uint4*>(&As[q][ldsOff1]) = ra1;
            *reinterpret_cast<uint4*>(&Bs[q][ldsOff0]) = rb0;
            *reinterpret_cast<uint4*>(&Bs[q][ldsOff1]) = rb1;
        }
        __syncthreads();                 // publish writes; gate next iter
        p ^= 1;
    }

    // Epilogue: C/D layout col = lane&15, row = (lane>>4)*4 + q  [m89/m91]
    const float alpha_v = to_vgpr(alpha);
    const float beta_v  = to_vgpr(beta);
    float lsum = 0.f;
    const int cr = lane >> 4;
    const int cc = lane & 15;
#pragma unroll
    for (int m = 0; m < 4; ++m) {
#pragma unroll
        for (int n = 0; n < 4; ++n) {
#pragma unroll
            for (int q = 0; q < 4; ++q) {
                const int gi = (int)i0 + wm * 64 + m * 16 + cr * 4 + q;
                const int gj = (int)j0 + wn * 64 + n * 16 + cc;
                float d = n2[gi] + n2[gj] - 2.f * acc[m][n][q];
                d = fmaxf(d, 0.f);
                float x = alpha_v + beta_v * d;
                float r = __frsqrt_rn(x);
                r = r * (1.5f - 0.5f * x * r * r);   // one Newton step
                lsum += r;
            }
        }
    }
    lsum *= w;

    __shared__ float red[256];
    red[t] = lsum;
    __syncthreads();
    for (int off = 128; off > 0; off >>= 1) {
        if (t < off) red[t] += red[t + off];
        __syncthreads();
    }
    if (t == 0) part[(size_t)region * NSLOT + swz] = (double)red[0];
}

// ---------------------------------------------------------------------------
// [fast path, zz] REG-STAGED whole-K kernel (K=64 fits LDS: 2x16KB).
// Straight-line staging (no arrays). One barrier total.  [r12-proven]
// ---------------------------------------------------------------------------
__global__ __launch_bounds__(256, 2)
void pair_zz_reg(const unsigned short* __restrict__ Z,   // 8192 x 64 bf16
                 const float* __restrict__ a2,
                 float alpha, float beta,
                 double* __restrict__ part)              // NBT x NBT
{
    const int bx = blockIdx.x;
    const int by = blockIdx.y;
    const int t  = threadIdx.x;
    if (bx < by) {
        if (t == 0) part[(size_t)by * NBT + bx] = 0.0;
        return;
    }
    const int lane = t & 63;
    const int wave = t >> 6;
    const int wm = wave >> 1;
    const int wn = wave & 1;
    const size_t i0 = (size_t)by * TILE;
    const size_t j0 = (size_t)bx * TILE;

    __shared__ __align__(16) unsigned short As[TILE * 64];
    __shared__ __align__(16) unsigned short Bs[TILE * 64];

    // Stage all 128x64 bf16 per matrix: 1024 x 16B chunks, 4 per thread.
#pragma unroll
    for (int s = 0; s < 4; ++s) {
        const int g    = s * 256 + t;
        const int row  = g >> 3;          // 0..127
        const int half = g & 7;           // 0..7
        const int halfS = half ^ (row & 7);
        uint4 va = *reinterpret_cast<const uint4*>(&Z[(i0 + row) * DLAT + half * 8]);
        uint4 vb = *reinterpret_cast<const uint4*>(&Z[(j0 + row) * DLAT + half * 8]);
        *reinterpret_cast<uint4*>(&As[row * 64 + halfS * 8]) = va;
        *reinterpret_cast<uint4*>(&Bs[row * 64 + halfS * 8]) = vb;
    }
    __syncthreads();

    f32x4 acc[4][4] = {};
    const int lr = lane & 15;
#pragma unroll
    for (int ks = 0; ks < 2; ++ks) {          // two K=32 steps
        const int kgg = ks * 4 + (lane >> 4); // global k-chunk 0..7
        bf16x8 af[4], bfr[4];
#pragma unroll
        for (int m = 0; m < 4; ++m) {
            const int rowA = wm * 64 + m * 16 + lr;
            af[m] = *reinterpret_cast<const bf16x8*>(
                &As[rowA * 64 + (kgg ^ (lr & 7)) * 8]);
        }
#pragma unroll
        for (int n = 0; n < 4; ++n) {
            const int rowB = wn * 64 + n * 16 + lr;
            bfr[n] = *reinterpret_cast<const bf16x8*>(
                &Bs[rowB * 64 + (kgg ^ (lr & 7)) * 8]);
        }
#pragma unroll
        for (int m = 0; m < 4; ++m)
#pragma unroll
            for (int n = 0; n < 4; ++n)
                acc[m][n] = __builtin_amdgcn_mfma_f32_16x16x32_bf16(
                    af[m], bfr[n], acc[m][n], 0, 0, 0);
    }

    const float alpha_v = to_vgpr(alpha);
    const float beta_v  = to_vgpr(beta);
    float lsum = 0.f;
    const int cr = lane >> 4;
    const int cc = lane & 15;
#pragma unroll
    for (int m = 0; m < 4; ++m) {
#pragma unroll
        for (int n = 0; n < 4; ++n) {
#pragma unroll
            for (int q = 0; q < 4; ++q) {
                const int gi = (int)i0 + wm * 64 + m * 16 + cr * 4 + q;
                const int gj = (int)j0 + wn * 64 + n * 16 + cc;
                float d = a2[gi] + a2[gj] - 2.f * acc[m][n][q];
                d = fmaxf(d, 0.f);
                float x = alpha_v + beta_v * d;
                float r = __frsqrt_rn(x);
                r = r * (1.5f - 0.5f * x * r * r);
                lsum += r;
            }
        }
    }
    if (bx > by) lsum *= 2.f;

    __shared__ float red[256];
    red[t] = lsum;
    __syncthreads();
    for (int off = 128; off > 0; off >>= 1) {
        if (t < off) red[t] += red[t + off];
        __syncthreads();
    }
    if (t == 0) part[(size_t)by * NBT + bx] = (double)red[0];
}

// ---------------------------------------------------------------------------
// [slow path fallback] round-3 verified kernels (+ constant-bus fix).
// ---------------------------------------------------------------------------
__global__ void rownorm_kernel(const float* __restrict__ dat,
                               const float* __restrict__ rec,
                               const float* __restrict__ z,
                               float* __restrict__ o_dat,
                               float* __restrict__ o_rec,
                               float* __restrict__ o_z)
{
    const float* X; float* O; int D;
    if (blockIdx.y == 0)      { X = dat; O = o_dat; D = DDAT; }
    else if (blockIdx.y == 1) { X = rec; O = o_rec; D = DDAT; }
    else                      { X = z;   O = o_z;   D = DLAT; }

    int row = blockIdx.x;
    float s = 0.f;
    for (int k = threadIdx.x; k < D; k += 256) {
        float v = X[(size_t)row * D + k];
        s += v * v;
    }
    __shared__ float sm[256];
    sm[threadIdx.x] = s;
    __syncthreads();
    for (int off = 128; off > 0; off >>= 1) {
        if (threadIdx.x < off) sm[threadIdx.x] += sm[threadIdx.x + off];
        __syncthreads();
    }
    if (threadIdx.x == 0) O[row] = sm[0];
}

__global__ __launch_bounds__(256, 2)
void pair_mfma_kernel(const float* __restrict__ A,
                      const float* __restrict__ B,
                      const float* __restrict__ a2,
                      const float* __restrict__ b2,
                      int D, float alpha, float beta, int sym,
                      double* __restrict__ part)
{
    const int bx = blockIdx.x;
    const int by = blockIdx.y;
    const int t  = threadIdx.x;
    if (sym && bx < by) {
        if (t == 0) part[(size_t)by * NBT + bx] = 0.0;
        return;
    }
    const int lane = t & 63;
    const int wave = t >> 6;
    const int wm = wave >> 1;
    const int wn = wave & 1;
    const int i0 = by * TILE;
    const int j0 = bx * TILE;

    __shared__ __align__(16) unsigned short As[TILE * 32];
    __shared__ __align__(16) unsigned short Bs[TILE * 32];

    f32x4 acc[4][4] = {};

    for (int k0 = 0; k0 < D; k0 += 32) {
        __syncthreads();
#pragma unroll
        for (int s = 0; s < 2; ++s) {
            const int g   = s * 256 + t;
            const int row = g >> 2;
            const int kb  = k0 + (g & 3) * 8;

            float va[8], vb[8];
            const float* srcA = &A[(size_t)(i0 + row) * D + kb];
            const float* srcB = &B[(size_t)(j0 + row) * D + kb];
            if (kb + 8 <= D) {
                float4 a0 = *reinterpret_cast<const float4*>(srcA);
                float4 a1 = *reinterpret_cast<const float4*>(srcA + 4);
                va[0]=a0.x; va[1]=a0.y; va[2]=a0.z; va[3]=a0.w;
                va[4]=a1.x; va[5]=a1.y; va[6]=a1.z; va[7]=a1.w;
                float4 b0 = *reinterpret_cast<const float4*>(srcB);
                float4 b1 = *reinterpret_cast<const float4*>(srcB + 4);
                vb[0]=b0.x; vb[1]=b0.y; vb[2]=b0.z; vb[3]=b0.w;
                vb[4]=b1.x; vb[5]=b1.y; vb[6]=b1.z; vb[7]=b1.w;
            } else {
#pragma unroll
                for (int c = 0; c < 8; ++c) {
                    va[c] = (kb + c < D) ? srcA[c] : 0.f;
                    vb[c] = (kb + c < D) ? srcB[c] : 0.f;
                }
            }
            bf16x8 pa, pb;
#pragma unroll
            for (int c = 0; c < 8; ++c) {
                __hip_bfloat16 ha = __float2bfloat16(va[c]);
                __hip_bfloat16 hb = __float2bfloat16(vb[c]);
                pa[c] = *reinterpret_cast<short*>(&ha);
                pb[c] = *reinterpret_cast<short*>(&hb);
            }
            *reinterpret_cast<bf16x8*>(&As[g * 8]) = pa;
            *reinterpret_cast<bf16x8*>(&Bs[g * 8]) = pb;
        }
        __syncthreads();

        const int lr = lane & 15;
        const int kg = lane >> 4;
        bf16x8 af[4], bfr[4];
#pragma unroll
        for (int m = 0; m < 4; ++m)
            af[m] = *reinterpret_cast<const bf16x8*>(
                &As[(wm * 64 + m * 16 + lr) * 32 + kg * 8]);
#pragma unroll
        for (int n = 0; n < 4; ++n)
            bfr[n] = *reinterpret_cast<const bf16x8*>(
                &Bs[(wn * 64 + n * 16 + lr) * 32 + kg * 8]);
#pragma unroll
        for (int m = 0; m < 4; ++m)
#pragma unroll
            for (int n = 0; n < 4; ++n)
                acc[m][n] = __builtin_amdgcn_mfma_f32_16x16x32_bf16(
                    af[m], bfr[n], acc[m][n], 0, 0, 0);
    }

    const float alpha_v = to_vgpr(alpha);
    const float beta_v  = to_vgpr(beta);
    float lsum = 0.f;
    const int cr = lane >> 4;
    const int cc = lane & 15;
#pragma unroll
    for (int m = 0; m < 4; ++m) {
#pragma unroll
        for (int n = 0; n < 4; ++n) {
#pragma unroll
            for (int q = 0; q < 4; ++q) {
                const int gi = i0 + wm * 64 + m * 16 + cr * 4 + q;
                const int gj = j0 + wn * 64 + n * 16 + cc;
                float d = a2[gi] + b2[gj] - 2.f * acc[m][n][q];
                d = fmaxf(d, 0.f);
                float x = alpha_v + beta_v * d;
                float r = __frsqrt_rn(x);
                r = r * (1.5f - 0.5f * x * r * r);
                lsum += r;
            }
        }
    }
    if (sym && bx > by) lsum *= 2.f;

    __shared__ float red[256];
    red[t] = lsum;
    __syncthreads();
    for (int off = 128; off > 0; off >>= 1) {
        if (t < off) red[t] += red[t + off];
        __syncthreads();
    }
    if (t == 0) part[(size_t)by * NBT + bx] = (double)red[0];
}

// ---------------------------------------------------------------------------
// Finalize (fast path): 3 region sums over NSLOT + zz over NPARTS + z norms.
// ---------------------------------------------------------------------------
__global__ void finalize_tri(const double* __restrict__ parts3,
                             const double* __restrict__ partsZ,
                             const float* __restrict__ z2,
                             float* __restrict__ out)
{
    const int tid = threadIdx.x;
    double s0 = 0, s1 = 0, s2 = 0, s3 = 0, s4 = 0;
    for (int i = tid; i < NSLOT; i += 256) {
        s0 += parts3[i];
        s1 += parts3[NSLOT + i];
        s2 += parts3[2 * NSLOT + i];
    }
    for (int i = tid; i < NPARTS; i += 256) s3 += partsZ[i];
    for (int i = tid; i < NROWS; i += 256) s4 += (double)z2[i];

    __shared__ double sm[256];
    double tot[5];
    double loc[5] = { s0, s1, s2, s3, s4 };
    for (int j = 0; j < 5; ++j) {
        sm[tid] = loc[j];
        __syncthreads();
        for (int off = 128; off > 0; off >>= 1) {
            if (tid < off) sm[tid] += sm[tid + off];
            __syncthreads();
        }
        tot[j] = sm[0];
        __syncthreads();
    }

    if (tid == 0) {
        const double Nn = (double)NROWS;
        const double n2 = Nn * Nn;
        const double y  = pow(4.0 / (3.0 * Nn), 0.4);

        double A = tot[0] / n2;
        double B = tot[1] / n2;
        double C = tot[2] / n2;
        double T = 1.0 / (2.0 * sqrt(M_PI * y));
        double loss_rec = log(T * (A + B - 2.0 * C));

        double An = tot[3] / n2;
        double B1 = tot[4];
        double Bn = 2.0 / sqrt(y + 0.5 + B1 / 125.0);
        double loss_norm = log(1.0 / sqrt(1.0 + y) + An - Bn);

        out[0] = (float)(loss_rec + loss_norm);
    }
}

// Finalize (slow path): round-3 layout (4 x NPARTS).
__global__ void finalize_kernel(const double* __restrict__ parts,
                                const float* __restrict__ z2,
                                float* __restrict__ out)
{
    const int tid = threadIdx.x;
    double s0 = 0, s1 = 0, s2 = 0, s3 = 0, s4 = 0;
    for (int i = tid; i < NPARTS; i += 256) {
        s0 += parts[i];
        s1 += parts[NPARTS + i];
        s2 += parts[2 * NPARTS + i];
        s3 += parts[3 * NPARTS + i];
    }
    for (int i = tid; i < NROWS; i += 256) s4 += (double)z2[i];

    __shared__ double sm[256];
    double tot[5];
    double loc[5] = { s0, s1, s2, s3, s4 };
    for (int j = 0; j < 5; ++j) {
        sm[tid] = loc[j];
        __syncthreads();
        for (int off = 128; off > 0; off >>= 1) {
            if (tid < off) sm[tid] += sm[tid + off];
            __syncthreads();
        }
        tot[j] = sm[0];
        __syncthreads();
    }

    if (tid == 0) {
        const double Nn = (double)NROWS;
        const double n2 = Nn * Nn;
        const double y  = pow(4.0 / (3.0 * Nn), 0.4);

        double A = tot[0] / n2;
        double B = tot[1] / n2;
        double C = tot[2] / n2;
        double T = 1.0 / (2.0 * sqrt(M_PI * y));
        double loss_rec = log(T * (A + B - 2.0 * C));

        double An = tot[3] / n2;
        double B1 = tot[4];
        double Bn = 2.0 / sqrt(y + 0.5 + B1 / 125.0);
        double loss_norm = log(1.0 / sqrt(1.0 + y) + An - Bn);

        out[0] = (float)(loss_rec + loss_norm);
    }
}

// ---------------------------------------------------------------------------
extern "C" void kernel_launch(void* const* d_in, const int* in_sizes, int n_in,
                              void* d_out, int out_size, void* d_ws, size_t ws_size,
                              hipStream_t stream)
{
    const float* data = (const float*)d_in[0];
    const float* rec  = (const float*)d_in[1];
    const float* z    = (const float*)d_in[2];
    float* out = (float*)d_out;

    // ws layout: [parts (3*NSLOT + NPARTS doubles, >= slow's 4*NPARTS)]
    //            [a2d a2r a2z][dat_bf rec_bf (concat) z_bf]
    const size_t PARTS_DBL = (size_t)3 * NSLOT + NPARTS;   // 30208 doubles
    char* ws = (char*)d_ws;
    double* parts3 = (double*)ws;
    double* partsZ = parts3 + (size_t)3 * NSLOT;
    float*  a2d    = (float*)(parts3 + PARTS_DBL);
    float*  a2r    = a2d + NROWS;     // adjacent: [a2d;a2r] = concat norms
    float*  a2z    = a2r + NROWS;
    unsigned short* dat_bf = (unsigned short*)(a2z + NROWS);
    unsigned short* rec_bf = dat_bf + (size_t)NROWS * LDK_D;  // adjacent: concat
    unsigned short* z_bf   = rec_bf + (size_t)NROWS * LDK_D;

    const size_t base_need = PARTS_DBL * sizeof(double) + 3 * (size_t)NROWS * sizeof(float);
    const size_t full_need = base_need +
        (2 * (size_t)NROWS * LDK_D + (size_t)NROWS * DLAT) * sizeof(unsigned short);
    const bool fast = (ws_size >= full_need);

    const double y = pow(4.0 / (3.0 * (double)NROWS), 0.4);
    const float beta_s = (float)(1.0 / (1565.0 * y));   // 2*DDAT-3 = 1565

    if (fast) {
        (void)hipMemsetAsync(parts3, 0, PARTS_DBL * sizeof(double), stream);
        convert_kernel<<<dim3(NROWS, 3), 256, 0, stream>>>(
            data, rec, z, dat_bf, rec_bf, z_bf, a2d, a2r, a2z);
        // dd + rr + dr in one supertiled triangular launch over concat
        pair_tri_reg<<<NSLOT, 256, 0, stream>>>(
            dat_bf, a2d, 1.0f, beta_s, parts3);
        // normality: z-z (symmetric), phi = rsqrt(y + dist/125)
        pair_zz_reg<<<dim3(NBT, NBT), 256, 0, stream>>>(
            z_bf, a2z, (float)y, 1.0f / 125.0f, partsZ);
        finalize_tri<<<1, 256, 0, stream>>>(parts3, partsZ, a2z, out);
    } else {
        double* parts = parts3;   // slow layout: 4 x NPARTS
        (void)hipMemsetAsync(parts, 0, 4 * (size_t)NPARTS * sizeof(double), stream);
        rownorm_kernel<<<dim3(NROWS, 3), 256, 0, stream>>>(
            data, rec, z, a2d, a2r, a2z);
        dim3 grid(NBT, NBT);
        pair_mfma_kernel<<<grid, 256, 0, stream>>>(
            data, data, a2d, a2d, DDAT, 1.0f, beta_s, 1, parts);
        pair_mfma_kernel<<<grid, 256, 0, stream>>>(
            rec, rec, a2r, a2r, DDAT, 1.0f, beta_s, 1, parts + NPARTS);
        pair_mfma_kernel<<<grid, 256, 0, stream>>>(
            data, rec, a2d, a2r, DDAT, 1.0f, beta_s, 0, parts + 2 * NPARTS);
        pair_mfma_kernel<<<grid, 256, 0, stream>>>(
            z, z, a2z, a2z, DLAT, (float)y, 1.0f / 125.0f, 1, parts + 3 * NPARTS);
        finalize_kernel<<<1, 256, 0, stream>>>(parts, a2z, out);
    }
}